// Round 7
// baseline (113.511 us; speedup 1.0000x reference)
//
#include <hip/hip_runtime.h>
#include <math.h>

#define BATCH 64
#define TT 24
#define HW 65536
#define PIX 50
#define NN 24
#define GAMMA_F 0.001f
#define INVG 1000.0f
#define BIGF 100000000.0f
#define NBIN 32768     // bins over ordered-key bits [31:17]
#define PARTS 4        // blocks per batch in local top-k
#define PSIZE (HW / PARTS)   // 16384 elements per part
#define CAPL 512       // candidate cap per part
#define NBLK 1600      // dtw blocks (2 problems each)
#define NCAND (PARTS * PIX)  // 200 candidates per batch

__device__ __forceinline__ unsigned ordered_key(float f) {
    unsigned u = __float_as_uint(f);
    return (u & 0x80000000u) ? ~u : (u | 0x80000000u);
}

// ---------------- Kernel 1: per-quarter exact local top-50 ---------------
// 256 blocks (4 per batch), 16K elements each: radix histogram + exact rank.
// Emits packed (key,~idx) u64 so that larger == better under
// (value desc, index asc) — exact lax.top_k tie semantics.
// Block 0 also re-zeros the dtw reduction state (visible at kernel boundary).
__global__ __launch_bounds__(1024) void topk_local_kernel(
        const float* __restrict__ mask, unsigned long long* __restrict__ cands,
        double* __restrict__ accS_d, double* __restrict__ accT_d,
        unsigned* __restrict__ counter) {
    __shared__ union {
        unsigned hist[NBIN];                                   // 128 KB
        struct { unsigned ck[CAPL]; unsigned ci[CAPL]; } c;    // 4 KB
    } U;
    __shared__ unsigned wtot[16], wsuf[16];
    __shared__ unsigned s_bin, ncand;

    const int tid  = threadIdx.x;
    const int w    = tid >> 6;
    const int lane = tid & 63;
    const int b    = blockIdx.x >> 2;
    const int part = blockIdx.x & 3;
    if (blockIdx.x == 0 && tid == 0) {        // reset dtw reduction state
        *accS_d = 0.0;
        *accT_d = 0.0;
        *counter = 0u;
    }
    if (tid == 0) ncand = 0;

    const float4* m4 = (const float4*)(mask + (size_t)b * HW + part * PSIZE);
    #pragma unroll
    for (int k = 0; k < NBIN / 1024; ++k) U.hist[tid + 1024 * k] = 0;
    __syncthreads();

    // ---- histogram over this part's 16K elements (4 float4 iters/thread) ----
    for (int c = tid; c < PSIZE / 4; c += 1024) {
        float4 v = m4[c];
        atomicAdd(&U.hist[ordered_key(v.x) >> 17], 1u);
        atomicAdd(&U.hist[ordered_key(v.y) >> 17], 1u);
        atomicAdd(&U.hist[ordered_key(v.z) >> 17], 1u);
        atomicAdd(&U.hist[ordered_key(v.w) >> 17], 1u);
    }
    __syncthreads();

    // ---- per-thread partial over 32 bins (rotated -> 2-way conflict, free) ----
    int base = tid * 32;
    int rot  = tid & 31;
    unsigned p = 0;
    #pragma unroll
    for (int k = 0; k < 32; ++k) p += U.hist[base + ((k + rot) & 31)];

    // wave-level inclusive suffix scan (registers)
    unsigned v = p;
    #pragma unroll
    for (int off = 1; off < 64; off <<= 1) {
        unsigned t = __shfl_down(v, off);
        if (lane + off < 64) v += t;
    }
    if (lane == 0) wtot[w] = v;
    __syncthreads();
    if (w == 0 && lane < 16) {
        unsigned x = wtot[lane];
        unsigned y = x;
        #pragma unroll
        for (int off = 1; off < 16; off <<= 1) {
            unsigned t = __shfl_down(y, off);
            if (lane + off < 16) y += t;
        }
        wsuf[lane] = y - x;           // exclusive suffix over higher waves
    }
    __syncthreads();

    {   // find crossing bin: max bin with S(bin) >= PIX (local k = 50)
        unsigned Sprev = (v - p) + wsuf[w];     // S(32t+32)
        for (int bsub = 31; bsub >= 0; --bsub) {
            unsigned S = Sprev + U.hist[base + bsub];
            if (S >= PIX && Sprev < PIX) s_bin = (unsigned)(base + bsub);
            Sprev = S;
        }
    }
    __syncthreads();                  // all hist reads done; cand may alias
    unsigned thresh = s_bin << 17;

    // ---- collect candidates from own slice (global within-batch index) ----
    for (int c = tid; c < PSIZE / 4; c += 1024) {
        float4 v4 = m4[c];
        float vv[4] = {v4.x, v4.y, v4.z, v4.w};
        #pragma unroll
        for (int e = 0; e < 4; ++e) {
            unsigned key = ordered_key(vv[e]);
            if (key >= thresh) {
                unsigned pos = atomicAdd(&ncand, 1u);
                if (pos < CAPL) {
                    U.c.ck[pos] = key;
                    U.c.ci[pos] = (unsigned)(part * PSIZE + 4 * c + e);
                }
            }
        }
    }
    __syncthreads();

    // ---- exact local ranking; write local top-50 packed ----
    int nc = (int)min(ncand, (unsigned)CAPL);
    for (int c = tid; c < nc; c += 1024) {
        unsigned long long me =
            ((unsigned long long)U.c.ck[c] << 32) | (unsigned long long)(~U.c.ci[c]);
        int rank = 0;
        for (int j = 0; j < nc; ++j) {
            unsigned long long o =
                ((unsigned long long)U.c.ck[j] << 32) | (unsigned long long)(~U.c.ci[j]);
            rank += (o > me);
        }
        if (rank < PIX) cands[(size_t)blockIdx.x * PIX + rank] = me;
    }
}

// ---------------- Kernel 2: merge-200 + soft-DTW fwd+bwd + fused reduce --
// One wave per block, 2 problems (lanes 0-23 / 32-55), register wavefront.
// Tail: device-scope f64 atomics (coherent point -> no fences), counter
// election; last block computes the final scalar.
__global__ __launch_bounds__(64, 2) void dtw_kernel(
        const float* __restrict__ pred, const float* __restrict__ truth,
        const unsigned long long* __restrict__ cands,
        double* __restrict__ accS_d, double* __restrict__ accT_d,
        unsigned* __restrict__ counter, float* __restrict__ out) {
    __shared__ unsigned long long cl[NCAND];
    __shared__ int topIdx[PIX];
    __shared__ float Rr[64][27];     // stride 27 floats: odd -> conflict-free
    __shared__ float P[64];

    const int lane = threadIdx.x;
    const int half = lane >> 5;
    const int r    = lane & 31;
    const bool rowAct = (r < NN);

    const int np  = 2 * blockIdx.x + half;    // global problem 0..3199
    const int b   = np / PIX;
    const int npb = np - b * PIX;             // within-batch problem 0..49

    // ---- merge this batch's 4x50 candidates -> exact batch top-50 ----
    for (int i = lane; i < NCAND; i += 64) cl[i] = cands[(size_t)b * NCAND + i];
    __syncthreads();
    for (int i = lane; i < NCAND; i += 64) {
        unsigned long long me = cl[i];
        int rank = 0;
        for (int j = 0; j < NCAND; ++j) rank += (cl[j] > me);
        if (rank < PIX) topIdx[rank] = (int)(~(unsigned)(me & 0xFFFFFFFFull));
    }
    __syncthreads();

    float tv = 0.0f, pv = 0.0f;
    if (rowAct) {
        int f  = npb * NN + r;                // within-batch flat (t,p) index
        int t  = f / PIX;
        int pp = f - t * PIX;
        size_t a = (size_t)(b * TT + t) * HW + (size_t)topIdx[pp];
        tv = truth[a];
        pv = pred[a];
    }
    P[lane] = pv;

    // ---- forward: lane r holds row i=r+1; step s computes R[i][s-i] ----
    float Rprev = BIGF, Rprev2 = BIGF;        // R[i][j-1], R[i][j-2]
    #pragma unroll
    for (int s = 2; s <= 2 * NN; ++s) {
        int j = s - 1 - r;
        bool act = rowAct && (j >= 1) && (j <= NN);
        float up   = __shfl_up(Rprev, 1);     // R[i-1][j]
        float diag = __shfl_up(Rprev2, 1);    // R[i-1][j-1]
        int jc = j - 1; jc = jc < 0 ? 0 : (jc > NN - 1 ? NN - 1 : jc);
        float pj = P[(half << 5) + jc];
        if (r == 0) { up = BIGF; diag = (s == 2) ? 0.0f : BIGF; }
        float mn = fminf(diag, fminf(up, Rprev));
        float z = __expf((mn - diag) * INVG) + __expf((mn - up) * INVG)
                + __expf((mn - Rprev) * INVG);
        float d = tv - pj;
        float Rnew = d * d + mn - GAMMA_F * __logf(z);
        if (act) {
            Rr[lane][j - 1] = Rnew;           // stage for backward
            Rprev2 = Rprev;
            Rprev  = Rnew;
        }
    }
    float accS = 0.0f, accT = 0.0f;
    if (r == NN - 1) accS = Rprev;            // R[24][24] (loss_shape)

    // ---- backward: E[i][j] = a*E[i+1][j] + b*E[i][j+1] + c*E[i+1][j+1] --
    float Eprev = 0.0f, Eprev2 = 0.0f;        // own E[i][j+1], E[i][j+2]
    if (r == NN - 1) Eprev = 1.0f;            // E[24][24]=1 (Omega term = 0)
    float tnext = __shfl_down(tv, 1);         // t[i] (row i+1's value)
    #pragma unroll
    for (int s = 2 * NN - 1; s >= 2; --s) {
        int j = s - 1 - r;
        bool act = rowAct && (j >= 1) && (j <= NN);
        float eUp   = __shfl_down(Eprev, 1);  // E[i+1][j]
        float eDiag = __shfl_down(Eprev2, 1); // E[i+1][j+1]
        int jc  = j - 1; jc  = jc  < 0 ? 0 : (jc  > NN - 1 ? NN - 1 : jc);
        int jc2 = j;     jc2 = jc2 < 0 ? 0 : (jc2 > NN - 1 ? NN - 1 : jc2);
        int lup = (r < NN - 1) ? lane + 1 : lane;
        float rij    = Rr[lane][jc];
        float rRight = (j >= NN)                ? -INFINITY : Rr[lane][jc2];
        float rDown  = (r == NN - 1)            ? -INFINITY : Rr[lup][jc];
        float rDiag  = (r == NN - 1 || j >= NN) ? -INFINITY : Rr[lup][jc2];
        float pjm1 = P[(half << 5) + jc];
        float pj   = P[(half << 5) + jc2];
        float da = tnext - pjm1; da *= da;    // D[i+1][j]
        float db = tv - pj;      db *= db;    // D[i][j+1]
        float dc = tnext - pj;   dc *= dc;    // D[i+1][j+1]
        float aw = __expf((rDown  - rij - da) * INVG);
        float bw = __expf((rRight - rij - db) * INVG);
        float cw = __expf((rDiag  - rij - dc) * INVG);
        float Enew = aw * eUp + bw * Eprev + cw * eDiag;
        if (act) {
            float dd = (float)(r + 1 - j);
            accT += Enew * dd * dd;           // E * Omega, own row slice
            Eprev2 = Eprev;
            Eprev  = Enew;
        }
    }

    // ---- wave butterfly (deterministic within block) ----
    #pragma unroll
    for (int off = 32; off > 0; off >>= 1) {
        accS += __shfl_xor(accS, off);
        accT += __shfl_xor(accT, off);
    }

    // ---- fused final reduction: device-scope atomics + election ----
    if (lane == 0) {
        double r1 = atomicAdd(accS_d, (double)accS);
        double r2 = atomicAdd(accT_d, (double)accT);
        // consume returns: forces vmcnt wait -> adds complete before counter
        asm volatile("" :: "v"(r1), "v"(r2) : "memory");
        unsigned old = atomicAdd(counter, 1u);
        if (old == NBLK - 1) {                // all partials have landed
            double S = atomicAdd(accS_d, 0.0);   // coherent read
            double T = atomicAdd(accT_d, 0.0);
            double loss_shape    = S / (double)(BATCH * PIX);
            double loss_temporal = T / ((double)(BATCH * PIX) * (double)(NN * NN));
            out[0] = (float)(0.1 * loss_shape + 0.9 * loss_temporal);
        }
    }
}

extern "C" void kernel_launch(void* const* d_in, const int* in_sizes, int n_in,
                              void* d_out, int out_size, void* d_ws, size_t ws_size,
                              hipStream_t stream) {
    const float* pred  = (const float*)d_in[0];
    const float* truth = (const float*)d_in[1];
    const float* mask  = (const float*)d_in[2];

    char* ws = (char*)d_ws;
    unsigned long long* cands = (unsigned long long*)ws;       // 256*50*8 = 102400 B
    double*   accS_d  = (double*)(ws + 102400);
    double*   accT_d  = (double*)(ws + 102408);
    unsigned* counter = (unsigned*)(ws + 102416);

    topk_local_kernel<<<BATCH * PARTS, 1024, 0, stream>>>(mask, cands, accS_d, accT_d, counter);
    dtw_kernel<<<NBLK, 64, 0, stream>>>(pred, truth, cands, accS_d, accT_d, counter, (float*)d_out);
}